// Round 1
// baseline (668.040 us; speedup 1.0000x reference)
//
#include <hip/hip_runtime.h>

// ---------------------------------------------------------------------------
// N=400000, E=2000000, B=8, C_IN=4, N_EDGE_TYPE=5, N_NODE_TYPE=7, C_OUT=32.
//
// HW model (measured R1-R5 prior session + rocprof this round):
//  - consume_kernel: 129us @ VALUBusy 11%, HBM 12%, occ 18.5% -> latency-bound
//  - hist/scatter: 245 blocks on 256 CUs -> under-occupied; scatter writes
//    sub-line multi-writer 8B records (R2/R4 bounce regime)
//  - R1: SPREAD global atomic dword RMW ~300G/s. The bad regimes were 64M
//    atomics (fallback) and hot-line returning atomics (R5).
//  => New primary path: accumulate pre-mix features agg[N][5][11] (88MB,
//     LLC-resident) with only 5 non-returning atomics/edge (10M total,
//     ~33us at R1 rate), then one dense BW-bound mix kernel.
//     Sort pipeline kept verbatim as fallback when workspace < 88MB.
// ---------------------------------------------------------------------------

#define CH     8192        // edges per chunk (sort fallback)
#define NBMAX  2048        // max 256-node buckets (N <= 524288)

// ---- temb stage 1 partials: emb @ W1 -> h1acc (pre-bias/swish) ------------
__global__ __launch_bounds__(64) void temb1_kernel(
    const float* __restrict__ t, const float* __restrict__ W1,
    float* __restrict__ h1acc)
{
    int jb = blockIdx.x & 7, ks = blockIdx.x >> 3;
    __shared__ float embs[8][32];
    int tid = threadIdx.x;
    const float kStep = 9.210340371976184f / 63.0f;
    for (int i = tid; i < 256; i += 64) {
        int b = i >> 5, kk = i & 31;
        int k = ks * 32 + kk;
        float v;
        if (k < 64) v = sinf(t[b] * expf(-(float)k * kStep));
        else        v = cosf(t[b] * expf(-(float)(k - 64) * kStep));
        embs[b][kk] = v;
    }
    __syncthreads();
    int j = jb * 64 + tid;
    float acc[8] = {};
    for (int kk = 0; kk < 32; ++kk) {
        float w = W1[(ks * 32 + kk) * 512 + j];
#pragma unroll
        for (int b = 0; b < 8; ++b) acc[b] += embs[b][kk] * w;
    }
#pragma unroll
    for (int b = 0; b < 8; ++b) atomicAdd(&h1acc[b * 512 + j], acc[b]);
}

// ---- temb stage 2 partials: swish(h1+b1) @ W2 -> h2acc --------------------
__global__ __launch_bounds__(64) void temb2_kernel(
    const float* __restrict__ h1acc, const float* __restrict__ b1,
    const float* __restrict__ W2, float* __restrict__ h2acc)
{
    int jb = blockIdx.x & 7, ks = blockIdx.x >> 3;
    __shared__ float h1s[8][64];
    int tid = threadIdx.x;
    for (int i = tid; i < 512; i += 64) {
        int b = i >> 6, kk = i & 63;
        int k = ks * 64 + kk;
        float v = h1acc[b * 512 + k] + b1[k];
        h1s[b][kk] = v / (1.0f + expf(-v));
    }
    __syncthreads();
    int j = jb * 64 + tid;
    float acc[8] = {};
    for (int kk = 0; kk < 64; ++kk) {
        float w = W2[(ks * 64 + kk) * 512 + j];
#pragma unroll
        for (int b = 0; b < 8; ++b) acc[b] += h1s[b][kk] * w;
    }
#pragma unroll
    for (int b = 0; b < 8; ++b) atomicAdd(&h2acc[b * 512 + j], acc[b]);
}

// ---- temb stage 3 partials: swish(h2+b2) @ W_temb -> inj[8,32] ------------
__global__ __launch_bounds__(256) void temb3_kernel(
    const float* __restrict__ h2acc, const float* __restrict__ b2,
    const float* __restrict__ Wt, float* __restrict__ inj)
{
    int ks = blockIdx.x;
    __shared__ float sws[8][64];
    int tid = threadIdx.x;
    for (int i = tid; i < 512; i += 256) {
        int b = i >> 6, kk = i & 63;
        int k = ks * 64 + kk;
        float v = h2acc[b * 512 + k] + b2[k];
        sws[b][kk] = v / (1.0f + expf(-v));
    }
    __syncthreads();
    int b = tid >> 5, c = tid & 31;
    float acc = 0.f;
    for (int kk = 0; kk < 64; ++kk)
        acc += sws[b][kk] * Wt[(ks * 64 + kk) * 32 + c];
    atomicAdd(&inj[tid], acc);
}

// ---- PRIMARY: per-edge 5 non-returning spread atomics into agg[N][55] -----
__global__ __launch_bounds__(256) void edge_atomic_kernel(
    const int* __restrict__ ei, const int* __restrict__ etype,
    const int* __restrict__ ntype, const float* __restrict__ x,
    float* __restrict__ agg, int E)
{
    int e = blockIdx.x * 256 + threadIdx.x;
    if (e >= E) return;
    int row = ei[e], col = ei[E + e];
    int T = etype[e], nt = ntype[col];
    float4 xv = ((const float4*)x)[col];
    float* a = agg + (size_t)row * 55 + T * 11;
    atomicAdd(a + 0, xv.x);
    atomicAdd(a + 1, xv.y);
    atomicAdd(a + 2, xv.z);
    atomicAdd(a + 3, xv.w);
    atomicAdd(a + 4 + nt, 1.0f);
}

// ---- PRIMARY: dense mix out = agg@W/5 + inj[batch]; coalesced, BW-bound ---
__global__ __launch_bounds__(256) void dense_kernel(
    const float* __restrict__ agg, const float* __restrict__ Wc,
    const int* __restrict__ batch, const float* __restrict__ inj,
    float* __restrict__ out, int N)
{
    __shared__ float tile[64 * 57];   // 64 nodes, stride 57 (odd -> banks)
    __shared__ float Ws[55 * 32];
    int tid = threadIdx.x;
    int n0 = blockIdx.x * 64;
    for (int i = tid; i < 55 * 32; i += 256) Ws[i] = Wc[i];
    int cnt = N - n0; if (cnt > 64) cnt = 64;
    int tot = cnt * 55;
    const float* src = agg + (size_t)n0 * 55;
    for (int i = tid; i < tot; i += 256) {
        int nl = i / 55, f = i - nl * 55;
        tile[nl * 57 + f] = src[i];
    }
    __syncthreads();
    for (int oi = tid; oi < cnt * 8; oi += 256) {
        int nl = oi >> 3, cq = oi & 7;
        int n = n0 + nl;
        const float* ar = tile + nl * 57;
        float4 acc = {0.f, 0.f, 0.f, 0.f};
#pragma unroll 5
        for (int f = 0; f < 55; ++f) {
            float a = ar[f];
            float4 w = *(const float4*)(Ws + f * 32 + cq * 4);
            acc.x += a * w.x;
            acc.y += a * w.y;
            acc.z += a * w.z;
            acc.w += a * w.w;
        }
        int bb = batch[n];
        float4 iv = ((const float4*)inj)[bb * 8 + cq];
        float4 o;
        o.x = iv.x + 0.2f * acc.x;
        o.y = iv.y + 0.2f * acc.y;
        o.z = iv.z + 0.2f * acc.z;
        o.w = iv.w + 0.2f * acc.w;
        ((float4*)out)[(size_t)n * 8 + cq] = o;
    }
}

// ---- hist: block per chunk; LDS histogram; contiguous row store -----------
__global__ __launch_bounds__(256) void hist_kernel(
    const int* __restrict__ ei, int* __restrict__ counts, int E, int NB)
{
    __shared__ int h[NBMAX];
    int tid = threadIdx.x;
    int c = blockIdx.x;
    for (int i = tid; i < NB; i += 256) h[i] = 0;
    __syncthreads();
    int s = c * CH, e = min(s + CH, E);
    for (int i = s + tid; i < e; i += 256)
        atomicAdd(&h[ei[i] >> 8], 1);
    __syncthreads();
    int* row = counts + (size_t)c * NB;
    for (int i = tid; i < NB; i += 256) row[i] = h[i];
}

// ---- scanA: per-block sums over bucket-major order j = b*NCH + c ----------
__global__ __launch_bounds__(256) void scanA_kernel(
    const int* __restrict__ counts, int* __restrict__ bsums,
    int M, int NB, int NCH)
{
    __shared__ int s[256];
    int tid = threadIdx.x;
    int j0 = blockIdx.x * 2048 + tid * 8;
    int p = 0;
#pragma unroll
    for (int k = 0; k < 8; ++k) {
        int j = j0 + k;
        if (j < M) {
            int b = j / NCH, c = j - b * NCH;
            p += counts[(size_t)c * NB + b];
        }
    }
    s[tid] = p; __syncthreads();
    for (int off = 128; off > 0; off >>= 1) {
        if (tid < off) s[tid] += s[tid + off];
        __syncthreads();
    }
    if (tid == 0) bsums[blockIdx.x] = s[0];
}

// ---- scanB: exclusive scan of block sums (single block, <=1024) -----------
__global__ __launch_bounds__(1024) void scanB_kernel(
    int* __restrict__ bsums, int* __restrict__ bstart, int nblk, int NB, int E)
{
    __shared__ int s[1024];
    int tid = threadIdx.x;
    int v = (tid < nblk) ? bsums[tid] : 0;
    s[tid] = v; __syncthreads();
    for (int off = 1; off < 1024; off <<= 1) {
        int u = (tid >= off) ? s[tid - off] : 0;
        __syncthreads();
        s[tid] += u;
        __syncthreads();
    }
    if (tid < nblk) bsums[tid] = s[tid] - v;          // exclusive
    if (tid == 0) bstart[NB] = E;
}

// ---- scanC: exact base for every (bucket, chunk) region + bstart ----------
__global__ __launch_bounds__(256) void scanC_kernel(
    const int* __restrict__ counts, const int* __restrict__ bsums,
    int* __restrict__ base, int* __restrict__ bstart,
    int M, int NB, int NCH)
{
    __shared__ int s[256];
    int tid = threadIdx.x;
    int j0 = blockIdx.x * 2048 + tid * 8;
    int v[8]; int p = 0;
#pragma unroll
    for (int k = 0; k < 8; ++k) {
        int j = j0 + k;
        v[k] = 0;
        if (j < M) {
            int b = j / NCH, c = j - b * NCH;
            v[k] = counts[(size_t)c * NB + b];
        }
        p += v[k];
    }
    s[tid] = p; __syncthreads();
    for (int off = 1; off < 256; off <<= 1) {
        int u = (tid >= off) ? s[tid - off] : 0;
        __syncthreads();
        s[tid] += u;
        __syncthreads();
    }
    int run = bsums[blockIdx.x] + (s[tid] - p);
#pragma unroll
    for (int k = 0; k < 8; ++k) {
        int j = j0 + k;
        if (j < M) {
            base[j] = run;
            int b = j / NCH, c = j - b * NCH;
            if (c == 0) bstart[b] = run;
            run += v[k];
        }
    }
}

// ---- scatter: block per chunk; LDS cursors from precomputed base ----------
__global__ __launch_bounds__(256) void scatter_kernel(
    const int* __restrict__ ei, const int* __restrict__ etype,
    const int* __restrict__ ntype, const int* __restrict__ base,
    uint2* __restrict__ rec, int E, int NB, int NCH)
{
    __shared__ int cur[NBMAX];
    int tid = threadIdx.x;
    int c = blockIdx.x;
    for (int b = tid; b < NB; b += 256)
        cur[b] = base[(size_t)b * NCH + c];
    __syncthreads();
    int s = c * CH, e = min(s + CH, E);
    for (int i = s + tid; i < e; i += 256) {
        int row = ei[i], col = ei[E + i];
        int T = etype[i], nt = ntype[col];
        int b = row >> 8;
        int slot = atomicAdd(&cur[b], 1);
        uint2 r;
        r.x = (unsigned)col | ((unsigned)T << 19) | ((unsigned)nt << 22);
        r.y = (unsigned)(row & 255);
        rec[slot] = r;
    }
}

// ---- consume: block per bucket; 5 LDS atomics/edge; dense epilogue --------
__global__ __launch_bounds__(256) void consume_kernel(
    const int* __restrict__ bstart, const uint2* __restrict__ rec,
    const float* __restrict__ x, const float* __restrict__ Wc,
    const int* __restrict__ batch, const float* __restrict__ inj,
    float* __restrict__ out, int N)
{
    __shared__ float tile[256 * 57];   // row stride 57 (odd -> spread banks)
    __shared__ float Ws[55 * 32];
    int tid = threadIdx.x;
    int b = blockIdx.x;
    for (int i = tid; i < 55 * 32; i += 256) Ws[i] = Wc[i];
    for (int i = tid; i < 256 * 57; i += 256) tile[i] = 0.f;
    __syncthreads();

    int s = bstart[b], e = bstart[b + 1];
    const uint2* src = rec;
#pragma unroll 2
    for (int i = s + tid; i < e; i += 256) {
        uint2 rc = src[i];
        int col  = rc.x & 0x7FFFF;
        int T    = (rc.x >> 19) & 7;
        int nt   = (rc.x >> 22) & 7;
        int lrow = (int)(rc.y & 255);
        float4 xv = ((const float4*)x)[col];
        float* tr = tile + lrow * 57 + T * 11;
        atomicAdd(tr + 0, xv.x);
        atomicAdd(tr + 1, xv.y);
        atomicAdd(tr + 2, xv.z);
        atomicAdd(tr + 3, xv.w);
        atomicAdd(tr + 4 + nt, 1.0f);
    }
    __syncthreads();

    int nodes = N - b * 256; if (nodes > 256) nodes = 256;
    for (int oi = tid; oi < nodes * 8; oi += 256) {
        int nl = oi >> 3, cq = oi & 7;
        int n = b * 256 + nl;
        const float* ar = tile + nl * 57;
        float4 acc = {0.f, 0.f, 0.f, 0.f};
#pragma unroll 5
        for (int f = 0; f < 55; ++f) {
            float a = ar[f];
            float4 w = *(const float4*)(Ws + f * 32 + cq * 4);
            acc.x += a * w.x;
            acc.y += a * w.y;
            acc.z += a * w.z;
            acc.w += a * w.w;
        }
        int bb = batch[n];
        float4 iv = ((const float4*)inj)[bb * 8 + cq];
        float4 o;
        o.x = iv.x + 0.2f * acc.x;
        o.y = iv.y + 0.2f * acc.y;
        o.z = iv.z + 0.2f * acc.z;
        o.w = iv.w + 0.2f * acc.w;
        ((float4*)out)[(size_t)n * 8 + cq] = o;
    }
}

// ---- fallback (guards fail): out init + direct atomic scatter (R1) --------
__global__ __launch_bounds__(256) void init_kernel(
    const int* __restrict__ batch_id, const float* __restrict__ inj,
    float4* __restrict__ out, int N)
{
    int gid = blockIdx.x * 256 + threadIdx.x;
    if (gid >= N * 8) return;
    int n = gid >> 3, q = gid & 7;
    int b = batch_id[n];
    out[gid] = ((const float4*)inj)[b * 8 + q];
}

__global__ __launch_bounds__(256) void edge_direct_kernel(
    const int* __restrict__ ei, const int* __restrict__ etype,
    const int* __restrict__ ntype, const float* __restrict__ x,
    const float* __restrict__ Wc, float* __restrict__ out, int E)
{
    __shared__ float Ws[55 * 32];
    for (int i = threadIdx.x; i < 55 * 32; i += 256) Ws[i] = Wc[i];
    __syncthreads();
    unsigned total = (unsigned)E * 32u;
    unsigned stride = gridDim.x * 256u;
    for (unsigned idx = blockIdx.x * 256u + threadIdx.x; idx < total;
         idx += stride) {
        int e = (int)(idx >> 5);
        int c = (int)(idx & 31);
        int row = ei[e];
        int col = ei[E + e];
        int T = etype[e];
        int nt = ntype[col];
        float4 xv = ((const float4*)x)[col];
        const float* wb = Ws + T * 352;
        float y = xv.x * wb[c] + xv.y * wb[32 + c] + xv.z * wb[64 + c] +
                  xv.w * wb[96 + c] + wb[(4 + nt) * 32 + c];
        atomicAdd(out + (size_t)row * 32 + c, y * 0.2f);
    }
}

extern "C" void kernel_launch(void* const* d_in, const int* in_sizes, int n_in,
                              void* d_out, int out_size, void* d_ws, size_t ws_size,
                              hipStream_t stream) {
    const float* x     = (const float*)d_in[0];   // [N,4]
    const float* t     = (const float*)d_in[1];   // [8]
    const int*   ei    = (const int*)d_in[2];     // [2,E]
    const int*   etype = (const int*)d_in[3];     // [E]
    const int*   ntype = (const int*)d_in[4];     // [N]
    const int*   batch = (const int*)d_in[5];     // [N]
    const float* Wc    = (const float*)d_in[6];   // [55,32]
    const float* W1    = (const float*)d_in[7];   // [128,512]
    const float* b1    = (const float*)d_in[8];   // [512]
    const float* W2    = (const float*)d_in[9];   // [512,512]
    const float* b2    = (const float*)d_in[10];  // [512]
    const float* Wt    = (const float*)d_in[11];  // [512,32]
    float* out = (float*)d_out;

    int E = in_sizes[3];
    int N = in_sizes[4];

    // ---- primary path workspace: temb accums + agg[N][55] -----------------
    float* ws     = (float*)d_ws;
    float* h1acc  = ws;                           // 4096
    float* h2acc  = ws + 4096;                    // 4096
    float* inj    = ws + 8192;                    // 256
    float* agg    = ws + 8448;                    // N*55
    size_t needA  = (8448 + (size_t)N * 55) * 4;
    bool okayA = (ws_size >= needA);

    // ---- sort-path workspace layout (fallback) ----------------------------
    int NB  = (N + 255) >> 8;                     // 256-node buckets
    int NCH = (E + CH - 1) / CH;                  // edge chunks
    size_t M = (size_t)NB * NCH;                  // scan length
    int nblkA = (int)((M + 2047) / 2048);

    int*   counts = (int*)(ws + 8448);            // NCH*NB  (cnt[c][b])
    int*   base   = counts + M;                   // NCH*NB  (base[j])
    int*   bsums  = base + M;                     // 1024
    int*   bstart = bsums + 1024;                 // NB+1
    size_t recOff = 8448 + 2 * M + 1024 + NB + 1;
    recOff = (recOff + 1) & ~(size_t)1;           // 8B align
    uint2* rec    = (uint2*)(ws + recOff);        // E records

    size_t needBytes = recOff * 4 + (size_t)E * 8;
    bool okay = (NB <= NBMAX) && (nblkA <= 1024) && (ws_size >= needBytes);

    if (okayA) {
        hipMemsetAsync(d_ws, 0, needA, stream);   // temb accums + agg

        temb1_kernel<<<32, 64, 0, stream>>>(t, W1, h1acc);
        temb2_kernel<<<64, 64, 0, stream>>>(h1acc, b1, W2, h2acc);
        temb3_kernel<<<8, 256, 0, stream>>>(h2acc, b2, Wt, inj);

        edge_atomic_kernel<<<(E + 255) / 256, 256, 0, stream>>>(
            ei, etype, ntype, x, agg, E);
        dense_kernel<<<(N + 63) / 64, 256, 0, stream>>>(
            agg, Wc, batch, inj, out, N);
    } else if (okay) {
        hipMemsetAsync(d_ws, 0, 8448 * 4, stream);   // temb accums only

        temb1_kernel<<<32, 64, 0, stream>>>(t, W1, h1acc);
        temb2_kernel<<<64, 64, 0, stream>>>(h1acc, b1, W2, h2acc);
        temb3_kernel<<<8, 256, 0, stream>>>(h2acc, b2, Wt, inj);

        hist_kernel<<<NCH, 256, 0, stream>>>(ei, counts, E, NB);
        scanA_kernel<<<nblkA, 256, 0, stream>>>(counts, bsums, (int)M, NB, NCH);
        scanB_kernel<<<1, 1024, 0, stream>>>(bsums, bstart, nblkA, NB, E);
        scanC_kernel<<<nblkA, 256, 0, stream>>>(counts, bsums, base, bstart,
                                                (int)M, NB, NCH);
        scatter_kernel<<<NCH, 256, 0, stream>>>(ei, etype, ntype, base, rec,
                                                E, NB, NCH);
        consume_kernel<<<NB, 256, 0, stream>>>(bstart, rec, x, Wc, batch, inj,
                                               out, N);
    } else {
        hipMemsetAsync(d_ws, 0, 8448 * 4, stream);
        temb1_kernel<<<32, 64, 0, stream>>>(t, W1, h1acc);
        temb2_kernel<<<64, 64, 0, stream>>>(h1acc, b1, W2, h2acc);
        temb3_kernel<<<8, 256, 0, stream>>>(h2acc, b2, Wt, inj);
        init_kernel<<<(N * 8 + 255) / 256, 256, 0, stream>>>(
            batch, inj, (float4*)out, N);
        edge_direct_kernel<<<16384, 256, 0, stream>>>(
            ei, etype, ntype, x, Wc, out, E);
    }
}

// Round 2
// 328.041 us; speedup vs baseline: 2.0365x; 2.0365x over previous
//
#include <hip/hip_runtime.h>

// ---------------------------------------------------------------------------
// N=400000, E=2000000, B=8, C_IN=4, N_EDGE_TYPE=5, N_NODE_TYPE=7, C_OUT=32.
//
// HW model (measured R1-R5 prior session + rounds 0-1 here):
//  - Global atomics into an N-sized fp32 buffer (88MB) thrash: every RMW
//    misses the 4MB per-XCD L2 -> 312MB writeback, 504us (round 1). DEAD END.
//  - Sort pipeline (round 0, 330us): consume 129us @ 18.5% occ (64KB LDS ->
//    2 blocks/CU), latency-bound (VALU 11%, HBM 12%); hist/scatter 245 blocks
//    -> 1 block/CU.
//  => This round: 128-node buckets (consume 4 blocks/CU), CH=2048 (scatter
//     ~4 blocks/CU), LDS-tiled transposes so all scan traffic is coalesced
//     (NCH padded to pow2 -> shift/mask), XCD-chunked swizzle in scatter so
//     rec-line co-writers stay on one XCD's L2.
// ---------------------------------------------------------------------------

#define CH     2048        // edges per chunk
#define BSZ    128         // nodes per bucket
#define BSH    7           // log2(BSZ)
#define NBMAX  4096        // max buckets (N <= 524288)

// ---- temb stage 1 partials: emb @ W1 -> h1acc (pre-bias/swish) ------------
__global__ __launch_bounds__(64) void temb1_kernel(
    const float* __restrict__ t, const float* __restrict__ W1,
    float* __restrict__ h1acc)
{
    int jb = blockIdx.x & 7, ks = blockIdx.x >> 3;
    __shared__ float embs[8][32];
    int tid = threadIdx.x;
    const float kStep = 9.210340371976184f / 63.0f;
    for (int i = tid; i < 256; i += 64) {
        int b = i >> 5, kk = i & 31;
        int k = ks * 32 + kk;
        float v;
        if (k < 64) v = sinf(t[b] * expf(-(float)k * kStep));
        else        v = cosf(t[b] * expf(-(float)(k - 64) * kStep));
        embs[b][kk] = v;
    }
    __syncthreads();
    int j = jb * 64 + tid;
    float acc[8] = {};
    for (int kk = 0; kk < 32; ++kk) {
        float w = W1[(ks * 32 + kk) * 512 + j];
#pragma unroll
        for (int b = 0; b < 8; ++b) acc[b] += embs[b][kk] * w;
    }
#pragma unroll
    for (int b = 0; b < 8; ++b) atomicAdd(&h1acc[b * 512 + j], acc[b]);
}

// ---- temb stage 2 partials: swish(h1+b1) @ W2 -> h2acc --------------------
__global__ __launch_bounds__(64) void temb2_kernel(
    const float* __restrict__ h1acc, const float* __restrict__ b1,
    const float* __restrict__ W2, float* __restrict__ h2acc)
{
    int jb = blockIdx.x & 7, ks = blockIdx.x >> 3;
    __shared__ float h1s[8][64];
    int tid = threadIdx.x;
    for (int i = tid; i < 512; i += 64) {
        int b = i >> 6, kk = i & 63;
        int k = ks * 64 + kk;
        float v = h1acc[b * 512 + k] + b1[k];
        h1s[b][kk] = v / (1.0f + expf(-v));
    }
    __syncthreads();
    int j = jb * 64 + tid;
    float acc[8] = {};
    for (int kk = 0; kk < 64; ++kk) {
        float w = W2[(ks * 64 + kk) * 512 + j];
#pragma unroll
        for (int b = 0; b < 8; ++b) acc[b] += h1s[b][kk] * w;
    }
#pragma unroll
    for (int b = 0; b < 8; ++b) atomicAdd(&h2acc[b * 512 + j], acc[b]);
}

// ---- temb stage 3 partials: swish(h2+b2) @ W_temb -> inj[8,32] ------------
__global__ __launch_bounds__(256) void temb3_kernel(
    const float* __restrict__ h2acc, const float* __restrict__ b2,
    const float* __restrict__ Wt, float* __restrict__ inj)
{
    int ks = blockIdx.x;
    __shared__ float sws[8][64];
    int tid = threadIdx.x;
    for (int i = tid; i < 512; i += 256) {
        int b = i >> 6, kk = i & 63;
        int k = ks * 64 + kk;
        float v = h2acc[b * 512 + k] + b2[k];
        sws[b][kk] = v / (1.0f + expf(-v));
    }
    __syncthreads();
    int b = tid >> 5, c = tid & 31;
    float acc = 0.f;
    for (int kk = 0; kk < 64; ++kk)
        acc += sws[b][kk] * Wt[(ks * 64 + kk) * 32 + c];
    atomicAdd(&inj[tid], acc);
}

// ---- hist: block per chunk (padded to NCHP); LDS histogram ----------------
__global__ __launch_bounds__(256) void hist_kernel(
    const int* __restrict__ ei, int* __restrict__ counts, int E, int NB)
{
    __shared__ int h[NBMAX];
    int tid = threadIdx.x;
    int c = blockIdx.x;
    for (int i = tid; i < NB; i += 256) h[i] = 0;
    __syncthreads();
    int s = c * CH, e = min(s + CH, E);
    for (int i = s + tid; i < e; i += 256)
        atomicAdd(&h[ei[i] >> BSH], 1);
    __syncthreads();
    int* row = counts + (size_t)c * NB;
    for (int i = tid; i < NB; i += 256) row[i] = h[i];
}

// ---- transpose: out[c*R + r] = in[r*C + c]; in is [R][C] ------------------
__global__ __launch_bounds__(256) void transpose_kernel(
    const int* __restrict__ in, int* __restrict__ outp, int R, int C)
{
    __shared__ int tile[32][33];
    int c0 = blockIdx.x * 32, r0 = blockIdx.y * 32;
    int tx = threadIdx.x & 31, ty = threadIdx.x >> 5;   // 32x8
#pragma unroll
    for (int k = 0; k < 4; ++k) {
        int r = r0 + ty + k * 8, c = c0 + tx;
        if (r < R && c < C) tile[ty + k * 8][tx] = in[(size_t)r * C + c];
    }
    __syncthreads();
#pragma unroll
    for (int k = 0; k < 4; ++k) {
        int c = c0 + ty + k * 8, r = r0 + tx;
        if (r < R && c < C) outp[(size_t)c * R + r] = tile[tx][ty + k * 8];
    }
}

// ---- scanA: per-block sums over linear countsT (bucket-major) -------------
__global__ __launch_bounds__(256) void scanA_kernel(
    const int* __restrict__ countsT, int* __restrict__ bsums, int M)
{
    __shared__ int s[256];
    int tid = threadIdx.x;
    int j0 = blockIdx.x * 4096 + tid * 16;
    int p = 0;
#pragma unroll
    for (int k = 0; k < 16; ++k) {
        int j = j0 + k;
        if (j < M) p += countsT[j];
    }
    s[tid] = p; __syncthreads();
    for (int off = 128; off > 0; off >>= 1) {
        if (tid < off) s[tid] += s[tid + off];
        __syncthreads();
    }
    if (tid == 0) bsums[blockIdx.x] = s[0];
}

// ---- scanB: exclusive scan of block sums (single block, <=1024) -----------
__global__ __launch_bounds__(1024) void scanB_kernel(
    int* __restrict__ bsums, int* __restrict__ bstart, int nblk, int NB, int E)
{
    __shared__ int s[1024];
    int tid = threadIdx.x;
    int v = (tid < nblk) ? bsums[tid] : 0;
    s[tid] = v; __syncthreads();
    for (int off = 1; off < 1024; off <<= 1) {
        int u = (tid >= off) ? s[tid - off] : 0;
        __syncthreads();
        s[tid] += u;
        __syncthreads();
    }
    if (tid < nblk) bsums[tid] = s[tid] - v;          // exclusive
    if (tid == 0) bstart[NB] = E;
}

// ---- scanC: exact base for every (bucket, chunk) region + bstart ----------
__global__ __launch_bounds__(256) void scanC_kernel(
    const int* __restrict__ countsT, const int* __restrict__ bsums,
    int* __restrict__ base, int* __restrict__ bstart, int M, int LOGC)
{
    __shared__ int s[256];
    int tid = threadIdx.x;
    int j0 = blockIdx.x * 4096 + tid * 16;
    int v[16]; int p = 0;
#pragma unroll
    for (int k = 0; k < 16; ++k) {
        int j = j0 + k;
        v[k] = (j < M) ? countsT[j] : 0;
        p += v[k];
    }
    s[tid] = p; __syncthreads();
    for (int off = 1; off < 256; off <<= 1) {
        int u = (tid >= off) ? s[tid - off] : 0;
        __syncthreads();
        s[tid] += u;
        __syncthreads();
    }
    int run = bsums[blockIdx.x] + (s[tid] - p);
    int maskC = (1 << LOGC) - 1;
#pragma unroll
    for (int k = 0; k < 16; ++k) {
        int j = j0 + k;
        if (j < M) {
            base[j] = run;
            if ((j & maskC) == 0) bstart[j >> LOGC] = run;
            run += v[k];
        }
    }
}

// ---- scatter: block per chunk; XCD-chunked swizzle; LDS cursors -----------
// rec = { col | T<<19 | nt<<22 , row&(BSZ-1) }
__global__ __launch_bounds__(256) void scatter_kernel(
    const int* __restrict__ ei, const int* __restrict__ etype,
    const int* __restrict__ ntype, const int* __restrict__ baseT,
    uint2* __restrict__ rec, int E, int NB)
{
    __shared__ int cur[NBMAX];
    int tid = threadIdx.x;
    // bijective XCD swizzle: consecutive chunks -> same XCD, so the co-writers
    // of each 64B rec line share one XCD's L2 (no cross-XCD line bounce).
    int nwg = gridDim.x;
    int q = nwg >> 3, r = nwg & 7;
    int xcd = blockIdx.x & 7, idx = blockIdx.x >> 3;
    int c = (xcd < r) ? xcd * (q + 1) + idx
                      : r * (q + 1) + (xcd - r) * q + idx;
    for (int b = tid; b < NB; b += 256)
        cur[b] = baseT[(size_t)c * NB + b];
    __syncthreads();
    int s = c * CH, e = min(s + CH, E);
    for (int i = s + tid; i < e; i += 256) {
        int row = ei[i], col = ei[E + i];
        int T = etype[i], nt = ntype[col];
        int b = row >> BSH;
        int slot = atomicAdd(&cur[b], 1);
        uint2 rc;
        rc.x = (unsigned)col | ((unsigned)T << 19) | ((unsigned)nt << 22);
        rc.y = (unsigned)(row & (BSZ - 1));
        rec[slot] = rc;
    }
}

// ---- consume: block per 128-node bucket; 5 LDS atomics/edge; dense mix ----
__global__ __launch_bounds__(256) void consume_kernel(
    const int* __restrict__ bstart, const uint2* __restrict__ rec,
    const float* __restrict__ x, const float* __restrict__ Wc,
    const int* __restrict__ batch, const float* __restrict__ inj,
    float* __restrict__ out, int N)
{
    __shared__ float tile[BSZ * 57];   // row stride 57 (odd -> spread banks)
    __shared__ float Ws[55 * 32];
    int tid = threadIdx.x;
    int b = blockIdx.x;
    for (int i = tid; i < 55 * 32; i += 256) Ws[i] = Wc[i];
    for (int i = tid; i < BSZ * 57; i += 256) tile[i] = 0.f;
    __syncthreads();

    int s = bstart[b], e = bstart[b + 1];
#pragma unroll 2
    for (int i = s + tid; i < e; i += 256) {
        uint2 rc = rec[i];
        int col  = rc.x & 0x7FFFF;
        int T    = (rc.x >> 19) & 7;
        int nt   = (rc.x >> 22) & 7;
        int lrow = (int)(rc.y & (BSZ - 1));
        float4 xv = ((const float4*)x)[col];
        float* tr = tile + lrow * 57 + T * 11;
        atomicAdd(tr + 0, xv.x);
        atomicAdd(tr + 1, xv.y);
        atomicAdd(tr + 2, xv.z);
        atomicAdd(tr + 3, xv.w);
        atomicAdd(tr + 4 + nt, 1.0f);
    }
    __syncthreads();

    int nodes = N - b * BSZ; if (nodes > BSZ) nodes = BSZ;
    for (int oi = tid; oi < nodes * 8; oi += 256) {
        int nl = oi >> 3, cq = oi & 7;
        int n = b * BSZ + nl;
        const float* ar = tile + nl * 57;
        float4 acc = {0.f, 0.f, 0.f, 0.f};
#pragma unroll 5
        for (int f = 0; f < 55; ++f) {
            float a = ar[f];
            float4 w = *(const float4*)(Ws + f * 32 + cq * 4);
            acc.x += a * w.x;
            acc.y += a * w.y;
            acc.z += a * w.z;
            acc.w += a * w.w;
        }
        int bb = batch[n];
        float4 iv = ((const float4*)inj)[bb * 8 + cq];
        float4 o;
        o.x = iv.x + 0.2f * acc.x;
        o.y = iv.y + 0.2f * acc.y;
        o.z = iv.z + 0.2f * acc.z;
        o.w = iv.w + 0.2f * acc.w;
        ((float4*)out)[(size_t)n * 8 + cq] = o;
    }
}

// ---- fallback (guards fail): out init + direct atomic scatter -------------
__global__ __launch_bounds__(256) void init_kernel(
    const int* __restrict__ batch_id, const float* __restrict__ inj,
    float4* __restrict__ out, int N)
{
    int gid = blockIdx.x * 256 + threadIdx.x;
    if (gid >= N * 8) return;
    int n = gid >> 3, q = gid & 7;
    int b = batch_id[n];
    out[gid] = ((const float4*)inj)[b * 8 + q];
}

__global__ __launch_bounds__(256) void edge_direct_kernel(
    const int* __restrict__ ei, const int* __restrict__ etype,
    const int* __restrict__ ntype, const float* __restrict__ x,
    const float* __restrict__ Wc, float* __restrict__ out, int E)
{
    __shared__ float Ws[55 * 32];
    for (int i = threadIdx.x; i < 55 * 32; i += 256) Ws[i] = Wc[i];
    __syncthreads();
    unsigned total = (unsigned)E * 32u;
    unsigned stride = gridDim.x * 256u;
    for (unsigned idx = blockIdx.x * 256u + threadIdx.x; idx < total;
         idx += stride) {
        int e = (int)(idx >> 5);
        int c = (int)(idx & 31);
        int row = ei[e];
        int col = ei[E + e];
        int T = etype[e];
        int nt = ntype[col];
        float4 xv = ((const float4*)x)[col];
        const float* wb = Ws + T * 352;
        float y = xv.x * wb[c] + xv.y * wb[32 + c] + xv.z * wb[64 + c] +
                  xv.w * wb[96 + c] + wb[(4 + nt) * 32 + c];
        atomicAdd(out + (size_t)row * 32 + c, y * 0.2f);
    }
}

extern "C" void kernel_launch(void* const* d_in, const int* in_sizes, int n_in,
                              void* d_out, int out_size, void* d_ws, size_t ws_size,
                              hipStream_t stream) {
    const float* x     = (const float*)d_in[0];   // [N,4]
    const float* t     = (const float*)d_in[1];   // [8]
    const int*   ei    = (const int*)d_in[2];     // [2,E]
    const int*   etype = (const int*)d_in[3];     // [E]
    const int*   ntype = (const int*)d_in[4];     // [N]
    const int*   batch = (const int*)d_in[5];     // [N]
    const float* Wc    = (const float*)d_in[6];   // [55,32]
    const float* W1    = (const float*)d_in[7];   // [128,512]
    const float* b1    = (const float*)d_in[8];   // [512]
    const float* W2    = (const float*)d_in[9];   // [512,512]
    const float* b2    = (const float*)d_in[10];  // [512]
    const float* Wt    = (const float*)d_in[11];  // [512,32]
    float* out = (float*)d_out;

    int E = in_sizes[3];
    int N = in_sizes[4];

    int NB  = (N + BSZ - 1) >> BSH;               // 128-node buckets
    int NCH = (E + CH - 1) / CH;                  // real edge chunks
    int NCHP = 1, LOGC = 0;                       // padded to pow2
    while (NCHP < NCH) { NCHP <<= 1; ++LOGC; }
    size_t M = (size_t)NB << LOGC;                // scan length
    int nblkA = (int)((M + 4095) / 4096);

    // ws layout (4-byte units)
    float* ws     = (float*)d_ws;
    float* h1acc  = ws;                           // 4096
    float* h2acc  = ws + 4096;                    // 4096
    float* inj    = ws + 8192;                    // 256
    int*   bufA   = (int*)(ws + 8448);            // M (counts, then base)
    int*   bufB   = bufA + M;                     // M (countsT, then baseT)
    int*   bsums  = bufB + M;                     // 1024
    int*   bstart = bsums + 1024;                 // NB+1
    size_t recOff = 8448 + 2 * M + 1024 + NB + 1;
    recOff = (recOff + 1) & ~(size_t)1;           // 8B align
    uint2* rec    = (uint2*)(ws + recOff);        // E records

    size_t needBytes = recOff * 4 + (size_t)E * 8;
    bool okay = (NB <= NBMAX) && (nblkA <= 1024) && (ws_size >= needBytes) &&
                (M < (size_t)1 << 30);

    if (okay) {
        hipMemsetAsync(d_ws, 0, 8448 * 4, stream);   // temb accums only

        temb1_kernel<<<32, 64, 0, stream>>>(t, W1, h1acc);
        temb2_kernel<<<64, 64, 0, stream>>>(h1acc, b1, W2, h2acc);
        temb3_kernel<<<8, 256, 0, stream>>>(h2acc, b2, Wt, inj);

        // counts[c][b] (chunk-major, coalesced writes)
        hist_kernel<<<NCHP, 256, 0, stream>>>(ei, bufA, E, NB);
        // countsT[b][c] (bucket-major, coalesced scan reads)
        transpose_kernel<<<dim3((NB + 31) / 32, (NCHP + 31) / 32),
                           dim3(256), 0, stream>>>(bufA, bufB, NCHP, NB);
        scanA_kernel<<<nblkA, 256, 0, stream>>>(bufB, bsums, (int)M);
        scanB_kernel<<<1, 1024, 0, stream>>>(bsums, bstart, nblkA, NB, E);
        // base[b][c] (linear writes) + bstart
        scanC_kernel<<<nblkA, 256, 0, stream>>>(bufB, bsums, bufA, bstart,
                                                (int)M, LOGC);
        // baseT[c][b] (coalesced cursor init in scatter)
        transpose_kernel<<<dim3((NCHP + 31) / 32, (NB + 31) / 32),
                           dim3(256), 0, stream>>>(bufA, bufB, NB, NCHP);
        scatter_kernel<<<NCH, 256, 0, stream>>>(ei, etype, ntype, bufB, rec,
                                                E, NB);
        consume_kernel<<<NB, 256, 0, stream>>>(bstart, rec, x, Wc, batch, inj,
                                               out, N);
    } else {
        hipMemsetAsync(d_ws, 0, 8448 * 4, stream);
        temb1_kernel<<<32, 64, 0, stream>>>(t, W1, h1acc);
        temb2_kernel<<<64, 64, 0, stream>>>(h1acc, b1, W2, h2acc);
        temb3_kernel<<<8, 256, 0, stream>>>(h2acc, b2, Wt, inj);
        init_kernel<<<(N * 8 + 255) / 256, 256, 0, stream>>>(
            batch, inj, (float4*)out, N);
        edge_direct_kernel<<<16384, 256, 0, stream>>>(
            ei, etype, ntype, x, Wc, out, E);
    }
}